// Round 3
// baseline (379.451 us; speedup 1.0000x reference)
//
#include <hip/hip_runtime.h>
#include <math.h>

// ---------------------------------------------------------------------------
// TemporalGCN: 2-layer LSTM (per-node sequences) -> 2 GCN rounds -> edge MLP.
//
// R11: R10 post-mortem: readlane broadcast moved the h-broadcast cost onto
// the VALU pipe and ADDED instructions (64 rdl + 192 fma vs 128 fma/seq);
// also default launch-bounds capped VGPR=92 < the 128 weight floats A-threads
// declare -> weight spills. Revert to R9's LDS-b128 broadcast dots, but cut
// its redundancy: in R9, B waves re-read h0_sh (16 b128/seq) for the xproj
// on top of h1_sh. Now A waves compute the xproj SHARING the float4 loads
// they already issue for the L0 gate dot (R10's 14-phase schedule, parity-
// double-buffered x1_sh). DS/phase: 1536 -> 1024 b128 (12.3K -> 8.2K clk).
// __launch_bounds__(512,2) keeps wh+wi1 resident.
//
// k_node: was ~40us vs 1.3us HBM roofline -- latency/serialization (single
// wave, 4 barriers, LDS h round-trips). GCN rounds + u/v now barrier-free,
// wave-redundant: h in registers (lane=unit), readlane broadcast (64/round),
// waves 0 and 1 run it independently. One barrier left (wsum). Identical
// FP accumulation order everywhere.
//
// k_mlp: was latency-bound (VGPR 92 -> no load pipelining of the 128
// dependent z1-loop loads). Loads batched 16-at-a-time into temps; compute
// unchanged (bit-identical order).
//
// Bit-exactness: all accumulation expressions replicated verbatim
// (quarter-split a0..a3 float4 dot, ascending-k fmaf chain + single bias
// add, c = fv*c + iv*gv, same shuffle trees) -> absmax 0.0 preserved.
// ---------------------------------------------------------------------------

#define Hd   64
#define Ed   5
#define Fd   6
#define Bd   8
#define Wd   12
#define Nd   200
#define NSEQ (Bd*Nd)        // 1600 sequences (b,n)
#define NG   (4*Hd)         // 256 gate rows
#define SEQPB 8             // sequences per fused-LSTM block (200 % 8 == 0)
#define LNEPS 1e-5f

__device__ __forceinline__ float sigm(float x) { return 1.0f / (1.0f + __expf(-x)); }
__device__ __forceinline__ float tanh_fast(float x) {
  float ax = fabsf(x);
  float t  = __expf(-2.0f * ax);
  float r  = (1.0f - t) / (1.0f + t);
  return copysignf(r, x);
}
// Broadcast lane l's value of v to all lanes via SGPR (VALU pipe, not DS).
__device__ __forceinline__ float rdl(float v, int l) {
  return __int_as_float(__builtin_amdgcn_readlane(__float_as_int(v), l));
}

// --------------------------------------------------------------------------
// Prep: gcnWT[round][k][u]; epWT[round][e][u]; W1aT[k][n]=W1[n][k];
// W1bT[k][n]=W1[n][64+k]. Sizes: 8192 + 640 + 4096 + 4096 = 17024 elements.
__global__ __launch_bounds__(256) void k_prep(
    const float* __restrict__ gcn_W, const float* __restrict__ ep_W,
    const float* __restrict__ W1,
    float* __restrict__ gcnWT, float* __restrict__ epWT,
    float* __restrict__ W1aT, float* __restrict__ W1bT)
{
  int idx = blockIdx.x * 256 + threadIdx.x;
  if (idx < 8192) {                        // gcnWT[r][k][u] = gcn_W[r][u][k]
    int round = idx >> 12, rem = idx & 4095;
    int k = rem >> 6, u = rem & 63;
    gcnWT[idx] = gcn_W[round * 4096 + u * 64 + k];
  } else if (idx < 8832) {                 // epWT[r][e][u] = ep_W[r][u][e]
    int r0 = idx - 8192;
    int round = r0 / 320, rem = r0 % 320;
    int e = rem >> 6, u = rem & 63;
    epWT[r0] = ep_W[round * 320 + u * Ed + e];
  } else if (idx < 12928) {                // W1aT[k][n] = W1[n][k]
    int r0 = idx - 8832;
    int k = r0 >> 6, n = r0 & 63;
    W1aT[r0] = W1[n * 133 + k];
  } else if (idx < 17024) {                // W1bT[k][n] = W1[n][64+k]
    int r0 = idx - 12928;
    int k = r0 >> 6, n = r0 & 63;
    W1bT[r0] = W1[n * 133 + 64 + k];
  }
}

// --------------------------------------------------------------------------
// Fused 2-layer LSTM. 200 blocks x 512 threads, 8 seqs/block.
// Phase t in [0,13]:
//   A waves (tid<256): L0 gates step t (t<12); xproj xv(t-1) (1<=t<=12),
//     sharing the same h0_sh float4 loads. xv -> x1_sh[t&1].
//   B waves: L1 gates step t-2 (t>=2), a0 seeded from x1_sh[(t-1)&1].
// Two barriers/phase (gate -> update -> next-gate hazards). Updates are
// partitioned (thread (w,u) owns seqs {w,w+4}, unit u), h stays in LDS.
__global__ __launch_bounds__(512, 2) void k_lstm_fused(
    const float* __restrict__ nf,                       // (B,W,N,F)
    const float* __restrict__ Wih0, const float* __restrict__ Whh0,
    const float* __restrict__ bih0, const float* __restrict__ bhh0,
    const float* __restrict__ Wih1, const float* __restrict__ Whh1,
    const float* __restrict__ bih1, const float* __restrict__ bhh1,
    float* __restrict__ hout)                           // (NSEQ, H)
{
  __shared__ float x_sh[SEQPB][Wd * Fd];   // 576
  __shared__ float h0_sh[SEQPB][Hd];       // 512
  __shared__ float h1_sh[SEQPB][Hd];       // 512
  __shared__ float g0_sh[SEQPB][NG];       // 2048 (post-activation gates L0)
  __shared__ float g1_sh[SEQPB][NG];       // 2048 (post-activation gates L1)
  __shared__ float x1_sh[2][SEQPB][NG];    // 4096 (xv, parity dbuf: A writes
                                           //  [t&1] while B reads [(t-1)&1])

  const int tid  = threadIdx.x;
  const int seq0 = blockIdx.x * SEQPB;
  const int b    = seq0 / Nd;              // uniform (200 % 8 == 0)
  const int n0   = seq0 % Nd;

  for (int idx = tid; idx < SEQPB * Wd * Fd; idx += 512) {
    int s = idx / (Wd * Fd), r = idx - s * (Wd * Fd);
    int t = r / Fd, f = r - t * Fd;
    x_sh[s][r] = nf[((b * Wd + t) * Nd + (n0 + s)) * Fd + f];
  }
  ((float*)h0_sh)[tid] = 0.f;              // 512 floats, one per thread
  ((float*)h1_sh)[tid] = 0.f;

  const bool isA = (tid < 256);
  const int j  = tid & 255;                // gate row within this layer
  const int jt = j >> 6;                   // 0=i,1=f,2=g,3=o (wave-uniform)
  const int u  = tid & 63;
  const int w  = (tid >> 6) & 3;           // owns seqs {w, w+4} in update

  // Per-thread weights (registers). launch_bounds(512,2) -> up to 256 VGPR.
  float4 wh[16];                           // Whh0 row j (A) / Whh1 row j (B)
  float4 wi1[16];                          // Wih1 row j (A only)
  float  wx[Fd];                           // Wih0 row j (A only)
  float  bias0 = 0.f, bias1 = 0.f;
  if (isA) {
    const float4* wr = (const float4*)(Whh0 + j * Hd);
    #pragma unroll
    for (int q = 0; q < 16; ++q) wh[q] = wr[q];
    #pragma unroll
    for (int f = 0; f < Fd; ++f) wx[f] = Wih0[j * Fd + f];
    bias0 = bih0[j] + bhh0[j];
    const float4* xr = (const float4*)(Wih1 + j * Hd);
    #pragma unroll
    for (int q = 0; q < 16; ++q) wi1[q] = xr[q];
    bias1 = bih1[j] + bhh1[j];
  } else {
    const float4* wr = (const float4*)(Whh1 + j * Hd);
    #pragma unroll
    for (int q = 0; q < 16; ++q) wh[q] = wr[q];
  }

  float cA = 0.f, cB = 0.f;                // cell states for seqs w, w+4
  float hA = 0.f, hB = 0.f;                // B threads: final h1 for w, w+4
  __syncthreads();

  for (int t = 0; t <= Wd + 1; ++t) {
    // ================= gate section ======================================
    if (isA) {
      if (t < Wd) {
        #pragma unroll 2
        for (int s = 0; s < SEQPB; ++s) {
          const float* xp = &x_sh[s][t * Fd];
          float a0 = bias0, a1 = 0.f, a2 = 0.f, a3 = 0.f;
          #pragma unroll
          for (int f = 0; f < Fd; ++f) a1 += xp[f] * wx[f];
          float xacc = 0.f;
          const float4* h4 = (const float4*)h0_sh[s];
          #pragma unroll
          for (int q = 0; q < 16; ++q) {
            float4 hv = h4[q];                      // ONE b128, two dots
            float d = hv.x * wh[q].x + hv.y * wh[q].y + hv.z * wh[q].z + hv.w * wh[q].w;
            if ((q & 3) == 0) a0 += d; else if ((q & 3) == 1) a1 += d;
            else if ((q & 3) == 2) a2 += d; else a3 += d;
            xacc = fmaf(hv.x, wi1[q].x, xacc);      // xproj for L1 step t-1
            xacc = fmaf(hv.y, wi1[q].y, xacc);
            xacc = fmaf(hv.z, wi1[q].z, xacc);
            xacc = fmaf(hv.w, wi1[q].w, xacc);
          }
          float acc = (a0 + a1) + (a2 + a3);
          g0_sh[s][j] = (jt == 2) ? tanh_fast(acc) : sigm(acc);
          if (t >= 1) x1_sh[t & 1][s][j] = xacc + bias1;
        }
      } else if (t == Wd) {                // t==12: xv(11) only
        #pragma unroll 2
        for (int s = 0; s < SEQPB; ++s) {
          float xacc = 0.f;
          const float4* h4 = (const float4*)h0_sh[s];
          #pragma unroll
          for (int q = 0; q < 16; ++q) {
            float4 hv = h4[q];
            xacc = fmaf(hv.x, wi1[q].x, xacc);
            xacc = fmaf(hv.y, wi1[q].y, xacc);
            xacc = fmaf(hv.z, wi1[q].z, xacc);
            xacc = fmaf(hv.w, wi1[q].w, xacc);
          }
          x1_sh[t & 1][s][j] = xacc + bias1;
        }
      }
    } else {
      if (t >= 2) {                        // L1 step t-2
        #pragma unroll 2
        for (int s = 0; s < SEQPB; ++s) {
          float a0 = x1_sh[(t - 1) & 1][s][j];   // xv(t-2), written phase t-1
          float a1 = 0.f, a2 = 0.f, a3 = 0.f;
          const float4* h4 = (const float4*)h1_sh[s];
          #pragma unroll
          for (int q = 0; q < 16; ++q) {
            float4 hv = h4[q];
            float d = hv.x * wh[q].x + hv.y * wh[q].y + hv.z * wh[q].z + hv.w * wh[q].w;
            if ((q & 3) == 0) a0 += d; else if ((q & 3) == 1) a1 += d;
            else if ((q & 3) == 2) a2 += d; else a3 += d;
          }
          float acc = (a0 + a1) + (a2 + a3);
          g1_sh[s][j] = (jt == 2) ? tanh_fast(acc) : sigm(acc);
        }
      }
    }
    __syncthreads();                       // gates ready; all h reads done

    // ================= update section (partitioned: (w,u) x {w,w+4}) =====
    if (isA) {
      if (t < Wd) {
        const float* gb = g0_sh[w];
        float iv = gb[u], fv = gb[64 + u], gv = gb[128 + u], ov = gb[192 + u];
        cA = fv * cA + iv * gv;
        hA = ov * tanh_fast(cA);
        h0_sh[w][u] = hA;
        const float* gb2 = g0_sh[w + 4];
        float iv2 = gb2[u], fv2 = gb2[64 + u], gv2 = gb2[128 + u], ov2 = gb2[192 + u];
        cB = fv2 * cB + iv2 * gv2;
        hB = ov2 * tanh_fast(cB);
        h0_sh[w + 4][u] = hB;
      }
    } else {
      if (t >= 2) {
        const float* gb = g1_sh[w];
        float iv = gb[u], fv = gb[64 + u], gv = gb[128 + u], ov = gb[192 + u];
        cA = fv * cA + iv * gv;
        hA = ov * tanh_fast(cA);
        h1_sh[w][u] = hA;
        const float* gb2 = g1_sh[w + 4];
        float iv2 = gb2[u], fv2 = gb2[64 + u], gv2 = gb2[128 + u], ov2 = gb2[192 + u];
        cB = fv2 * cB + iv2 * gv2;
        hB = ov2 * tanh_fast(cB);
        h1_sh[w + 4][u] = hB;
      }
    }
    __syncthreads();                       // h writes visible to next phase
  }

  // Final h1(11) -> hout from B threads' partitioned state. Coalesced.
  if (!isA) {
    hout[(seq0 + w) * Hd + u]     = hA;
    hout[(seq0 + w + 4) * Hd + u] = hB;
  }
}

// --------------------------------------------------------------------------
// Fused per-row node pipeline: wsum -> GCN r0 -> GCN r1 -> u/v precompute.
// One block per row (b,i); 256 threads. wsum uses the ORIGINAL 256-thread
// partition + shuffle tree (bit-identical). After the single wsum barrier,
// waves 0 and 1 independently run the GCN rounds wave-redundantly with h in
// registers (lane = unit) and readlane broadcast -- no barriers, no LDS h.
// Wave 0 finishes with uu, wave 1 with vt. Waves 2-3 exit after wsum.
__global__ __launch_bounds__(256) void k_node(
    const float* __restrict__ ef,    const float* __restrict__ adj,
    const float* __restrict__ h0,
    const float* __restrict__ gcnWT, const float* __restrict__ gcn_b,
    const float* __restrict__ epWT,  const float* __restrict__ ep_b,
    const float* __restrict__ ln_g,  const float* __restrict__ ln_b,
    const float* __restrict__ W1aT,  const float* __restrict__ W1bT,
    const float* __restrict__ b1,
    float* __restrict__ uu, float* __restrict__ vt)
{
  __shared__ float ef_sh[Nd * Ed];   // 1000: edge_last row (coalesced stage)
  __shared__ float adj_sh[Nd];       // 200
  __shared__ float red[4][6];

  const int row = blockIdx.x;      // b*200+i
  const int b = row / Nd, i = row % Nd;
  const int tid = threadIdx.x;
  const int lane = tid & 63;
  const int wv = tid >> 6;

  const float* efrow = ef + (size_t)(((b * Wd + (Wd - 1)) * Nd + i)) * (Nd * Ed);
  for (int idx = tid; idx < Nd * Ed; idx += 256) ef_sh[idx] = efrow[idx];
  const float* adjrow = adj + (b * Nd + i) * Nd;
  if (tid < Nd) adj_sh[tid] = adjrow[tid];
  float hreg = h0[row * Hd + lane];  // lane = unit (per-wave copy)
  __syncthreads();

  // ---- wsum: IDENTICAL partition + tree to previous version (bit-exact)
  float p[6] = {0.f, 0.f, 0.f, 0.f, 0.f, 0.f};
  if (tid < Nd) {
    float a = adj_sh[tid];
    p[5] = a;
    #pragma unroll
    for (int k = 0; k < Ed; ++k) p[k] = a * ef_sh[tid * Ed + k];
  }
  #pragma unroll
  for (int k = 0; k < 6; ++k) {
    float v = p[k];
    for (int off = 32; off > 0; off >>= 1) v += __shfl_down(v, off);
    p[k] = v;
  }
  if (lane == 0) {
    #pragma unroll
    for (int k = 0; k < 6; ++k) red[wv][k] = p[k];
  }
  __syncthreads();                 // the ONLY barrier after staging

  if (wv >= 2) return;             // no further barriers below

  float w6r[6];
  #pragma unroll
  for (int k = 0; k < 6; ++k)
    w6r[k] = red[0][k] + red[1][k] + red[2][k] + red[3][k];  // same order

  // ---- 2 GCN rounds, wave-redundant, barrier-free (readlane broadcast)
  #pragma unroll
  for (int round = 0; round < 2; ++round) {
    const float* gwT = gcnWT + round * 4096;   // [k][u]
    const float* ewT = epWT  + round * 320;    // [e][u]
    float acc = gcn_b[round * Hd + lane] + w6r[5] * ep_b[round * Hd + lane];
    #pragma unroll
    for (int e = 0; e < Ed; ++e) acc += w6r[e] * ewT[e * 64 + lane];
    #pragma unroll
    for (int k = 0; k < Hd; ++k) acc += rdl(hreg, k) * gwT[k * 64 + lane];

    float mu = acc;
    #pragma unroll
    for (int off = 1; off < 64; off <<= 1) mu += __shfl_xor(mu, off);
    mu *= (1.f / 64.f);
    float d = acc - mu;
    float var = d * d;
    #pragma unroll
    for (int off = 1; off < 64; off <<= 1) var += __shfl_xor(var, off);
    var *= (1.f / 64.f);
    float v = d * rsqrtf(var + LNEPS) * ln_g[round * Hd + lane] + ln_b[round * Hd + lane];
    hreg = fmaxf(v, 0.f);
  }

  // ---- u/v precompute: wave 0 -> uu, wave 1 -> vt (same exprs as before)
  if (wv == 0) {
    float acc = b1[lane];
    #pragma unroll
    for (int k = 0; k < Hd; ++k) acc += rdl(hreg, k) * W1aT[k * 64 + lane];
    uu[row * Hd + lane] = acc;
  } else {
    float acc = 0.f;
    #pragma unroll
    for (int k = 0; k < Hd; ++k) acc += rdl(hreg, k) * W1bT[k * 64 + lane];
    vt[lane * NSEQ + row] = acc;
  }
}

// --------------------------------------------------------------------------
// Edge MLP: thread per edge. z1[64] lives in VGPRs; W1c/W2/W3/b2 have
// wave-uniform indices -> scalar-pipe loads. uu/vt loads batched 16-at-a-
// time into temps so the compiler can pipeline them (was load-use serial).
__global__ __launch_bounds__(256) void k_mlp(
    const float* __restrict__ ef,
    const float* __restrict__ u, const float* __restrict__ vt,
    const float* __restrict__ W1,
    const float* __restrict__ W2, const float* __restrict__ b2,
    const float* __restrict__ W3, const float* __restrict__ b3,
    float* __restrict__ out)
{
  const int idx = blockIdx.x * 256 + threadIdx.x;   // < 320000
  const int b   = idx / (Nd * Nd);
  const int rem = idx - b * Nd * Nd;
  const int i   = rem / Nd;
  const int jj  = rem - i * Nd;

  const float* e = ef + (((b * Wd + (Wd - 1)) * Nd + i) * Nd + jj) * Ed;
  float e5[Ed];
  #pragma unroll
  for (int q = 0; q < Ed; ++q) e5[q] = e[q];

  const float* ur = u + (b * Nd + i) * Hd;
  const int vcol = b * Nd + jj;

  float z1[64];
  #pragma unroll
  for (int kb = 0; kb < 8; ++kb) {
    float uvv[8], vvv[8];                         // 16 loads issued together
    #pragma unroll
    for (int q = 0; q < 8; ++q) {
      uvv[q] = ur[kb * 8 + q];
      vvv[q] = vt[(kb * 8 + q) * NSEQ + vcol];
    }
    #pragma unroll
    for (int q = 0; q < 8; ++q) {
      int k = kb * 8 + q;
      float acc = uvv[q] + vvv[q];                // same order as ur[k]+vt[..]
      const float* w1c = W1 + k * 133 + 128;      // uniform -> scalar loads
      #pragma unroll
      for (int qq = 0; qq < Ed; ++qq) acc += e5[qq] * w1c[qq];
      z1[k] = fmaxf(acc, 0.f);
    }
  }

  float logit = b3[0];
  #pragma unroll 4
  for (int o = 0; o < 32; ++o) {
    float a0 = b2[o], a1 = 0.f, a2 = 0.f, a3 = 0.f;
    const float* w2 = W2 + o * 64;              // uniform -> scalar loads
    #pragma unroll
    for (int k = 0; k < 64; k += 4) {
      a0 += w2[k]     * z1[k];
      a1 += w2[k + 1] * z1[k + 1];
      a2 += w2[k + 2] * z1[k + 2];
      a3 += w2[k + 3] * z1[k + 3];
    }
    float z2 = fmaxf((a0 + a1) + (a2 + a3), 0.f);
    logit += W3[o] * z2;
  }
  out[idx] = 1.f / (1.f + __expf(-logit));
}

// --------------------------------------------------------------------------
extern "C" void kernel_launch(void* const* d_in, const int* in_sizes, int n_in,
                              void* d_out, int out_size, void* d_ws, size_t ws_size,
                              hipStream_t stream) {
  (void)in_sizes; (void)n_in; (void)out_size; (void)ws_size;
  const float* nf   = (const float*)d_in[0];
  const float* ef   = (const float*)d_in[1];
  const float* adj  = (const float*)d_in[2];
  const float* Wih0 = (const float*)d_in[3];
  const float* Whh0 = (const float*)d_in[4];
  const float* bih0 = (const float*)d_in[5];
  const float* bhh0 = (const float*)d_in[6];
  const float* Wih1 = (const float*)d_in[7];
  const float* Whh1 = (const float*)d_in[8];
  const float* bih1 = (const float*)d_in[9];
  const float* bhh1 = (const float*)d_in[10];
  const float* gcnW = (const float*)d_in[11];
  const float* gcnB = (const float*)d_in[12];
  const float* epW  = (const float*)d_in[13];
  const float* epB  = (const float*)d_in[14];
  const float* lnG  = (const float*)d_in[15];
  const float* lnB  = (const float*)d_in[16];
  const float* W1   = (const float*)d_in[17];
  const float* b1   = (const float*)d_in[18];
  const float* W2   = (const float*)d_in[19];
  const float* b2   = (const float*)d_in[20];
  const float* W3   = (const float*)d_in[21];
  const float* b3   = (const float*)d_in[22];
  float* out = (float*)d_out;

  // Workspace layout (floats).
  float* ws   = (float*)d_ws;
  float* h0   = ws;                        // 102,400
  float* uu   = h0   + 102400;             // 102,400
  float* vt   = uu   + 102400;             // 102,400
  float* gWT  = vt   + 102400;             // 8,192
  float* eWT  = gWT  + 8192;               // 640
  float* W1aT = eWT  + 640;                // 4,096
  float* W1bT = W1aT + 4096;               // 4,096

  k_prep      <<<67,        256, 0, stream>>>(gcnW, epW, W1, gWT, eWT, W1aT, W1bT);
  k_lstm_fused<<<NSEQ/SEQPB,512, 0, stream>>>(nf, Wih0, Whh0, bih0, bhh0,
                                              Wih1, Whh1, bih1, bhh1, h0);
  k_node      <<<1600,      256, 0, stream>>>(ef, adj, h0, gWT, gcnB, eWT, epB,
                                              lnG, lnB, W1aT, W1bT, b1, uu, vt);
  k_mlp       <<<1250,      256, 0, stream>>>(ef, uu, vt, W1, W2, b2, W3, b3, out);
}